// Round 2
// baseline (139.922 us; speedup 1.0000x reference)
//
#include <hip/hip_runtime.h>
#include <hip/hip_bf16.h>
#include <cstdint>

typedef __attribute__((ext_vector_type(8))) short  short8;   // 8 x bf16 (4 VGPR)
typedef __attribute__((ext_vector_type(4))) float  f32x4;
typedef __attribute__((ext_vector_type(4))) unsigned uint4v;

#define N_ROWS   4096
#define IN_DIM   256
#define OUT_DIM  256
#define GRIDSZ   32
#define K_TOTAL  16384      // IN_DIM * GRIDSZ * 2
#define SPLITK   8
#define KCHUNK   2048       // K_TOTAL / SPLITK
#define BM       128
#define BK       64
#define STEPS    32         // KCHUNK / BK == #i handled per block

// ---------------------------------------------------------------------------
// BmatT[j][k] (bf16), k = i*64 + g*2 + p ; p=0 -> cos coeffs, p=1 -> sin.
// coeffs layout: [2][out][in][grid] fp32.
__global__ void convert_coeffs(const float* __restrict__ w,
                               __hip_bfloat16* __restrict__ bm) {
    int gid = blockIdx.x * 256 + threadIdx.x;      // 0 .. 256*16384-1
    int j = gid >> 14;
    int k = gid & (K_TOTAL - 1);
    int i = k >> 6;
    int r = k & 63;
    int g = r >> 1;
    int p = r & 1;
    float v = w[(((p << 8) + j) * 256 + i) * 32 + g];
    bm[gid] = __float2bfloat16(v);
}

__global__ void bias_fill(const float* __restrict__ bias, float* __restrict__ out) {
    int gid = blockIdx.x * 256 + threadIdx.x;
    out[gid] = bias[gid & (OUT_DIM - 1)];
}

// ---------------------------------------------------------------------------
__device__ __forceinline__ void gld_lds16(const void* g, void* l) {
    // dest is wave-uniform base; HW writes lane*16B. CK-style uintptr AS casts.
    __builtin_amdgcn_global_load_lds(
        (const __attribute__((address_space(1))) void*)(uintptr_t)g,
        (__attribute__((address_space(3))) void*)(uintptr_t)l, 16, 0, 0);
}

// round-to-nearest-even f32 -> bf16 (non-NaN inputs), returned in low 16 bits
__device__ __forceinline__ unsigned f2bf(float f) {
    unsigned u = __builtin_bit_cast(unsigned, f);
    return (u + 0x7fffu + ((u >> 16) & 1u)) >> 16;
}

__global__ __launch_bounds__(512, 2) void fkan_gemm(const float* __restrict__ x,
                                                    const __hip_bfloat16* __restrict__ bm,
                                                    float* __restrict__ out) {
    __shared__ float  x_lds[STEPS][BM];        // 16 KiB, transposed: [i_local][m]
    __shared__ short  A_lds[2][BM * BK];       // 32 KiB, XOR-swizzled 16B chunks
    __shared__ short  B_lds[2][OUT_DIM * BK];  // 64 KiB, swizzle via global src perm

    const int tid  = threadIdx.x;
    const int lane = tid & 63;
    const int wid  = tid >> 6;      // 8 waves
    const int wm   = wid >> 2;      // 0..1  -> 64-row slice
    const int wn   = wid & 3;       // 0..3  -> 64-col slice

    const int bid = blockIdx.x;
    const int ks  = bid & 7;        // k-split; ties B-panel to one XCD's L2
    const int mb  = bid >> 3;
    const int m0  = mb * BM;
    const int i0  = ks * STEPS;
    const int kbase = ks * KCHUNK;

    // ---- stage x panel transposed: x_lds[i_local][m] ----
    #pragma unroll
    for (int s2 = 0; s2 < 2; ++s2) {
        int slot = tid + s2 * 512;              // 1024 float4 slots
        int m  = slot >> 3;
        int c4 = slot & 7;
        f32x4 xv = *(const f32x4*)&x[(m0 + m) * IN_DIM + i0 + c4 * 4];
        #pragma unroll
        for (int q = 0; q < 4; ++q) x_lds[c4 * 4 + q][m] = xv[q];
    }
    __syncthreads();

    f32x4 acc[4][4];
    #pragma unroll
    for (int a = 0; a < 4; ++a)
        #pragma unroll
        for (int b = 0; b < 4; ++b) acc[a][b] = (f32x4){0.f, 0.f, 0.f, 0.f};

    const int am = tid & 127;   // A-gen: row this thread generates
    const int ah = tid >> 7;    // A-gen: segment (8 multipliers each)

    auto stage_B = [&](int s, int buf) {
        int kg = kbase + s * BK;
        #pragma unroll
        for (int r = 0; r < 4; ++r) {
            int jl = wid * 32 + r * 8 + (lane >> 3);          // LDS row this lane fills
            int cg = (lane & 7) ^ (jl & 7);                   // inverse-swizzled src chunk
            const __hip_bfloat16* src = bm + jl * K_TOTAL + kg + cg * 8;
            gld_lds16(src, &B_lds[buf][(wid * 32 + r * 8) * BK]);
        }
    };

    auto gen_A = [&](int s, int buf) {
        float xv = x_lds[s][am];
        float c1, s1; __sincosf(xv, &s1, &c1);                         // cis(x)
        float cg, sg; __sincosf((float)(8 * ah + 1) * xv, &sg, &cg);   // cis((8h+1)x)
        unsigned pk[8];
        #pragma unroll
        for (int e = 0; e < 8; ++e) {
            pk[e] = f2bf(cg) | (f2bf(sg) << 16);             // even kloc=cos, odd=sin
            float cn = cg * c1 - sg * s1;                    // cis((g+1)x)=cis(gx)cis(x)
            sg = sg * c1 + cg * s1;
            cg = cn;
        }
        int base = am * BK;
        uint4v w0 = {pk[0], pk[1], pk[2], pk[3]};
        uint4v w1 = {pk[4], pk[5], pk[6], pk[7]};
        *(uint4v*)&A_lds[buf][base + (((2 * ah    ) ^ (am & 7)) << 3)] = w0;
        *(uint4v*)&A_lds[buf][base + (((2 * ah + 1) ^ (am & 7)) << 3)] = w1;
    };

    auto compute = [&](int buf) {
        const int rA = lane & 15;
        const int cA = lane >> 4;
        #pragma unroll
        for (int kf = 0; kf < 2; ++kf) {
            short8 af[4], bf[4];
            #pragma unroll
            for (int mf = 0; mf < 4; ++mf) {
                int row = wm * 64 + mf * 16 + rA;
                int ch  = (kf * 4 + cA) ^ (rA & 7);
                af[mf] = *(const short8*)&A_lds[buf][row * BK + ch * 8];
            }
            #pragma unroll
            for (int nf = 0; nf < 4; ++nf) {
                int row = wn * 64 + nf * 16 + rA;
                int ch  = (kf * 4 + cA) ^ (rA & 7);
                bf[nf] = *(const short8*)&B_lds[buf][row * BK + ch * 8];
            }
            #pragma unroll
            for (int mf = 0; mf < 4; ++mf)
                #pragma unroll
                for (int nf = 0; nf < 4; ++nf)
                    acc[mf][nf] = __builtin_amdgcn_mfma_f32_16x16x32_bf16(
                        af[mf], bf[nf], acc[mf][nf], 0, 0, 0);
        }
    };

    // T3-minimum double-buffered pipeline: one barrier per K-step,
    // next-tile loads issued before the MFMA cluster so vmcnt drains cheap.
    stage_B(0, 0);
    gen_A(0, 0);
    int cur = 0;
    for (int s = 0; s < STEPS; ++s) {
        __syncthreads();
        if (s + 1 < STEPS) { stage_B(s + 1, cur ^ 1); gen_A(s + 1, cur ^ 1); }
        compute(cur);
        cur ^= 1;
    }

    // epilogue: C/D layout col=lane&15, row=(lane>>4)*4+reg (m89-verified)
    const int cl = lane & 15;
    const int rl = (lane >> 4) * 4;
    #pragma unroll
    for (int mf = 0; mf < 4; ++mf) {
        #pragma unroll
        for (int nf = 0; nf < 4; ++nf) {
            int row = m0 + wm * 64 + mf * 16 + rl;
            int col = wn * 64 + nf * 16 + cl;
            #pragma unroll
            for (int r2 = 0; r2 < 4; ++r2)
                atomicAdd(&out[(row + r2) * OUT_DIM + col], acc[mf][nf][r2]);
        }
    }
}

// ---------------------------------------------------------------------------
extern "C" void kernel_launch(void* const* d_in, const int* in_sizes, int n_in,
                              void* d_out, int out_size, void* d_ws, size_t ws_size,
                              hipStream_t stream) {
    const float* x      = (const float*)d_in[0];   // [4096,256] f32
    const float* coeffs = (const float*)d_in[1];   // [2,256,256,32] f32
    const float* bias   = (const float*)d_in[2];   // [1,256] f32
    float* out = (float*)d_out;                    // [4096,256] f32
    __hip_bfloat16* bmat = (__hip_bfloat16*)d_ws;  // needs 8 MiB

    convert_coeffs<<<(OUT_DIM * K_TOTAL) / 256, 256, 0, stream>>>(coeffs, bmat);
    bias_fill<<<(N_ROWS * OUT_DIM) / 256, 256, 0, stream>>>(bias, out);
    fkan_gemm<<<SPLITK * (N_ROWS / BM), 512, 0, stream>>>(x, bmat, out);
}